// Round 4
// baseline (6152.739 us; speedup 1.0000x reference)
//
#include <hip/hip_runtime.h>
#include <hip/hip_bf16.h>
#include <cstdint>
#include <cstddef>

#define BB 64
#define TT 512
#define DD 256
#define HH 512
#define G4 2048   // 4*H

typedef __bf16 bf16x8 __attribute__((ext_vector_type(8)));
typedef __bf16 bf16x4 __attribute__((ext_vector_type(4)));
typedef float  f32x4  __attribute__((ext_vector_type(4)));
typedef unsigned long long u64;

__device__ __forceinline__ float sigf(float x) {
  return 1.0f / (1.0f + __expf(-x));
}

__device__ __forceinline__ void drain_vmem() {
  asm volatile("s_waitcnt vmcnt(0)" ::: "memory");
}

// Convert x fp32 [B][T][D] -> bf16 (same layout) in ws.
__global__ void cvt_x_kernel(const float* __restrict__ x, __bf16* __restrict__ xb) {
  int i = (blockIdx.x * 256 + threadIdx.x) * 4;
  float4 v = *(const float4*)(x + i);
  bf16x4 o;
  o[0] = (__bf16)v.x; o[1] = (__bf16)v.y; o[2] = (__bf16)v.z; o[3] = (__bf16)v.w;
  *(bf16x4*)(xb + i) = o;
}

// Persistent bidirectional LSTM, gate-split to kill register spill.
// Grid: 64 blocks x 512 threads (8 waves). dir = blockIdx>>5, s = blockIdx&31
// owns hidden units [16s,16s+16). Wave (mt,gp): mt = M-tile (16 batch rows),
// gp = gate pair (0: i,f ; 1: g,o). Weight B-fragments per wave: wfrag[2][24]
// = 192 VGPRs (was 384 -> spilled). Gate combine via 8KB LDS exchange; c-state
// lives in gp=0 waves. Cross-block h exchange identical to R3 (write-through
// relaxed agent atomics, LLC-read atomic loads, no fences). Wave 0 polls the
// 32 remote flags, broadcasts via LDS token.
__launch_bounds__(512, 1)
__global__ void lstm_kernel(const __bf16* __restrict__ xb,
                            const float* __restrict__ Wf, const float* __restrict__ Uf,
                            const float* __restrict__ bf_,
                            const float* __restrict__ Wb, const float* __restrict__ Ub,
                            const float* __restrict__ bb_,
                            __bf16* __restrict__ hbuf,           // [2 dir][2 phase][64][512]
                            unsigned int* __restrict__ flags,    // [2][32] stride 32 uints
                            float* __restrict__ out,             // d_out
                            __bf16* __restrict__ hsb) {          // [T][B][H] bwd halves
  __shared__ float zbuf[8 * 4 * 64];   // [r*2+g2][mt][lane]
  __shared__ unsigned int token;

  const int bx  = blockIdx.x;
  const int dir = bx >> 5;
  const int s   = bx & 31;
  const float* Wd = dir ? Wb : Wf;
  const float* Ud = dir ? Ub : Uf;
  const float* bd = dir ? bb_ : bf_;
  unsigned int* flbase = flags + (size_t)dir * 32 * 32;   // 32 flags, 128B apart
  unsigned int* myflag = flbase + (size_t)s * 32;
  __bf16* hb = hbuf + (size_t)dir * 2 * BB * HH;

  const int tid  = threadIdx.x;
  const int wv   = tid >> 6;
  const int lane = tid & 63;
  const int mt   = wv & 3;        // M-tile (16 batch rows)
  const int gp   = wv >> 2;       // gate pair: 0 -> {i,f}, 1 -> {g,o}
  const int j    = lane & 15;     // A row offset / B col / D col
  const int q    = lane >> 4;     // quad
  const int colg = s * 16 + j;    // hidden unit index this lane owns

  if (tid == 0) token = 0;

  // ---- gather weight B-fragments (one-time): 2 gates x 24 k-tiles ----
  bf16x8 wfrag[2][24];
#pragma unroll
  for (int g2 = 0; g2 < 2; ++g2) {
    const int col = (gp * 2 + g2) * HH + colg;
#pragma unroll
    for (int kt = 0; kt < 24; ++kt) {
      bf16x8 v;
#pragma unroll
      for (int e = 0; e < 8; ++e) {
        const int k = kt * 32 + q * 8 + e;
        const float w = (k < DD) ? Wd[(size_t)k * G4 + col]
                                 : Ud[(size_t)(k - DD) * G4 + col];
        v[e] = (__bf16)w;
      }
      wfrag[g2][kt] = v;
    }
  }
  float bg2[2];
#pragma unroll
  for (int g2 = 0; g2 < 2; ++g2) bg2[g2] = bd[(gp * 2 + g2) * HH + colg];

  __syncthreads();   // token init visible

  float cst[4] = {0.f, 0.f, 0.f, 0.f};   // cell state (gp=0 waves only)
  const size_t outTail = (size_t)BB * TT * HH;
  unsigned int* pollp = flbase + (size_t)(lane & 31) * 32;

  for (int tau = 0; tau < TT; ++tau) {
    const int t = dir ? (TT - 1 - tau) : tau;

    // x-part (independent of h): issue before the spin
    const __bf16* xrow = xb + ((size_t)(mt * 16 + j) * TT + t) * DD + q * 8;
    f32x4 acc[2];
#pragma unroll
    for (int g2 = 0; g2 < 2; ++g2)
      acc[g2] = (f32x4){bg2[g2], bg2[g2], bg2[g2], bg2[g2]};
#pragma unroll
    for (int kt = 0; kt < 8; ++kt) {
      bf16x8 a = *(const bf16x8*)(xrow + kt * 32);
      acc[0] = __builtin_amdgcn_mfma_f32_16x16x32_bf16(a, wfrag[0][kt], acc[0], 0, 0, 0);
      acc[1] = __builtin_amdgcn_mfma_f32_16x16x32_bf16(a, wfrag[1][kt], acc[1], 0, 0, 0);
    }

    // wait for h_tau: wave 0 polls the 32 remote flags, broadcasts LDS token
    if (tau) {
      const unsigned int target = (unsigned int)tau;
      if (wv == 0) {
        for (;;) {
          unsigned int v = __hip_atomic_load(pollp, __ATOMIC_RELAXED, __HIP_MEMORY_SCOPE_AGENT);
          if (__all((int)(v >= target))) break;
          __builtin_amdgcn_s_sleep(2);
        }
        if (lane == 0)
          __hip_atomic_store(&token, target, __ATOMIC_RELAXED, __HIP_MEMORY_SCOPE_WORKGROUP);
      } else {
        while (__hip_atomic_load(&token, __ATOMIC_RELAXED, __HIP_MEMORY_SCOPE_WORKGROUP) < target)
          __builtin_amdgcn_s_sleep(1);
      }
      asm volatile("" ::: "memory");
    }

    // h-part: LLC-direct 8B atomic loads
    const u64* hrow = (const u64*)(hb + (size_t)(tau & 1) * (BB * HH)
                                   + (size_t)(mt * 16 + j) * HH) + q * 2;
#pragma unroll
    for (int kt = 0; kt < 16; ++kt) {
      u64 lo = __hip_atomic_load(hrow + kt * 8,     __ATOMIC_RELAXED, __HIP_MEMORY_SCOPE_AGENT);
      u64 hi = __hip_atomic_load(hrow + kt * 8 + 1, __ATOMIC_RELAXED, __HIP_MEMORY_SCOPE_AGENT);
      union { u64 u[2]; bf16x8 v; } tmp;
      tmp.u[0] = lo; tmp.u[1] = hi;
      acc[0] = __builtin_amdgcn_mfma_f32_16x16x32_bf16(tmp.v, wfrag[0][8 + kt], acc[0], 0, 0, 0);
      acc[1] = __builtin_amdgcn_mfma_f32_16x16x32_bf16(tmp.v, wfrag[1][8 + kt], acc[1], 0, 0, 0);
    }

    // gate exchange: gp=1 publishes z_g, z_o
    if (gp == 1) {
#pragma unroll
      for (int r = 0; r < 4; ++r) {
        zbuf[((r * 2 + 0) * 4 + mt) * 64 + lane] = acc[0][r];   // z_g
        zbuf[((r * 2 + 1) * 4 + mt) * 64 + lane] = acc[1][r];   // z_o
      }
    }
    __syncthreads();   // B1: z visible to gp=0

    if (gp == 0) {
      unsigned int* hnext = (unsigned int*)(hb + (size_t)((tau + 1) & 1) * (BB * HH));
#pragma unroll
      for (int r = 0; r < 4; ++r) {
        const float zi = acc[0][r], zf = acc[1][r];
        const float zg = zbuf[((r * 2 + 0) * 4 + mt) * 64 + lane];
        const float zo = zbuf[((r * 2 + 1) * 4 + mt) * 64 + lane];
        const float gi = sigf(zi), gf = sigf(zf), gg = sigf(zg), go = sigf(zo);
        const float cn = gf * cst[r] + gi * gg;
        cst[r] = cn;
        const float hn = go * sigf(cn);
        const int orow = mt * 16 + q * 4 + r;     // batch row

        // pack 2 adjacent units (lanes j, j^1 share q & rows), write-through
        const unsigned int mine = (unsigned int)__builtin_bit_cast(unsigned short, (__bf16)hn);
        const unsigned int other = (unsigned int)__shfl_xor((int)mine, 1, 64);
        if (!(j & 1)) {
          const unsigned int packed = (other << 16) | mine;  // low addr = even unit
          __hip_atomic_store(hnext + ((size_t)orow * HH + colg) / 2, packed,
                             __ATOMIC_RELAXED, __HIP_MEMORY_SCOPE_AGENT);
        }

        if (dir == 0) {
          __builtin_nontemporal_store(0.5f * hn,
              out + (size_t)orow * (TT * HH) + (size_t)t * HH + colg);
        } else {
          __builtin_nontemporal_store((__bf16)hn,
              hsb + (size_t)t * (BB * HH) + (size_t)orow * HH + colg);
        }
        if (tau == TT - 1) {
          float* base = out + outTail + (size_t)dir * (2 * BB * HH);
          __builtin_nontemporal_store(hn, base + (size_t)orow * HH + colg);            // hF/hB
          __builtin_nontemporal_store(cn, base + (size_t)BB * HH + (size_t)orow * HH + colg); // cF/cB
        }
      }
      drain_vmem();    // h write-throughs acked by LLC
    }
    __syncthreads();   // B2: all gp=0 stores drained
    if (tid == 0)
      __hip_atomic_store(myflag, (unsigned int)(tau + 1), __ATOMIC_RELAXED,
                         __HIP_MEMORY_SCOPE_AGENT);
  }
}

// out[b,t,c] += 0.5 * hsb[t,b,c]
__global__ void combine_kernel(float* __restrict__ out, const __bf16* __restrict__ hsb) {
  const size_t i = ((size_t)blockIdx.x * 256 + threadIdx.x) * 4;
  const size_t b = i >> 18;
  const size_t t = (i >> 9) & 511;
  const size_t c = i & 511;
  bf16x4 hv = *(const bf16x4*)(hsb + t * (BB * HH) + b * HH + c);
  float4 v = *(float4*)(out + i);
  v.x += 0.5f * (float)hv[0];
  v.y += 0.5f * (float)hv[1];
  v.z += 0.5f * (float)hv[2];
  v.w += 0.5f * (float)hv[3];
  *(float4*)(out + i) = v;
}

extern "C" void kernel_launch(void* const* d_in, const int* in_sizes, int n_in,
                              void* d_out, int out_size, void* d_ws, size_t ws_size,
                              hipStream_t stream) {
  (void)in_sizes; (void)n_in; (void)out_size; (void)ws_size;
  const float* x   = (const float*)d_in[0];
  // d_in[1] = 'hidden' is unused by the reference (h0 = c0 = 0)
  const float* Wf  = (const float*)d_in[2];
  const float* Uf  = (const float*)d_in[3];
  const float* bf_ = (const float*)d_in[4];
  const float* Wb  = (const float*)d_in[5];
  const float* Ub  = (const float*)d_in[6];
  const float* bb_ = (const float*)d_in[7];
  float* out = (float*)d_out;
  char* ws = (char*)d_ws;

  // ws layout:
  //   [0, 8K)         : flags  2 dir x 32 blocks, 128B apart
  //   [8K, ~270K)     : hbuf   2 dir x 2 phase x 64 x 512 bf16
  //   [512K, 16.5M)   : x bf16 [B][T][D]
  //   [16.5M, 48.5M)  : hsb bf16 [T][B][H]
  unsigned int* flags = (unsigned int*)ws;
  __bf16* hbuf = (__bf16*)(ws + 8192);
  __bf16* xb   = (__bf16*)(ws + (1 << 19));
  __bf16* hsb  = (__bf16*)(ws + (1 << 19) + (size_t)BB * TT * DD * 2);

  hipMemsetAsync(ws, 0, 1 << 19, stream);  // zero flags + h ping-pong (h0 = 0)
  cvt_x_kernel<<<dim3((BB * TT * DD) / 1024), dim3(256), 0, stream>>>(x, xb);
  lstm_kernel<<<dim3(64), dim3(512), 0, stream>>>(xb, Wf, Uf, bf_, Wb, Ub, bb_,
                                                  hbuf, flags, out, hsb);
  combine_kernel<<<dim3((BB * TT * HH) / 1024), dim3(256), 0, stream>>>(out, hsb);
}